// Round 1
// baseline (1144.900 us; speedup 1.0000x reference)
//
#include <hip/hip_runtime.h>
#include <cmath>

#define NN 8192
#define DD 512
#define NSRC 8
#define SPLITS 8
#define TM 64
#define TN 64
#define TK 16
#define CPS (NN / SPLITS)      // columns per split = 1024
#define CTILES (CPS / TN)      // 16

// ---------------------------------------------------------------------------
// Kernel 1: per-source text sums T[s][d] and per-source counts.
// 64 blocks x 256 threads; each block owns 128 rows; each thread owns 2 d-cols
// (conflict-free LDS accumulation, atomic flush to global).
// ---------------------------------------------------------------------------
__global__ __launch_bounds__(256) void k_src_sums(
    const float* __restrict__ txt, const int* __restrict__ labels,
    float* __restrict__ Tsum, int* __restrict__ counts)
{
    __shared__ float Tacc[NSRC * DD];
    __shared__ int cacc[NSRC];
    const int tid = threadIdx.x;
    const int d0 = 2 * tid;
#pragma unroll
    for (int s = 0; s < NSRC; s++) {
        Tacc[s * DD + d0] = 0.f;
        Tacc[s * DD + d0 + 1] = 0.f;
    }
    if (tid < NSRC) cacc[tid] = 0;
    __syncthreads();

    const int row0 = blockIdx.x * 128;
    if (tid < 128) atomicAdd(&cacc[labels[row0 + tid]], 1);

    for (int j = 0; j < 128; j++) {
        const int lab = labels[row0 + j];
        const float2 v = *(const float2*)(txt + (size_t)(row0 + j) * DD + d0);
        Tacc[lab * DD + d0]     += v.x;
        Tacc[lab * DD + d0 + 1] += v.y;
    }
    __syncthreads();
#pragma unroll
    for (int s = 0; s < NSRC; s++) {
        atomicAdd(&Tsum[s * DD + d0],     Tacc[s * DD + d0]);
        atomicAdd(&Tsum[s * DD + d0 + 1], Tacc[s * DD + d0 + 1]);
    }
    if (tid < NSRC) atomicAdd(&counts[tid], cacc[tid]);
}

// ---------------------------------------------------------------------------
// Kernel 2: online logsumexp over logits rows, tiled fp32 GEMM.
// Block = 256 threads, computes TM=64 rows vs a 1/SPLITS column slice.
// Writes per-(row, split) partial (m, s) to workspace.
// ---------------------------------------------------------------------------
__global__ __launch_bounds__(256) void k_lse(
    const float* __restrict__ img, const float* __restrict__ txt,
    const float* __restrict__ scale_p,
    float* __restrict__ pm, float* __restrict__ ps)
{
    __shared__ float As[TK][TM];
    __shared__ float Bs[TK][TN];
    const float scale = scale_p[0];
    const int tid = threadIdx.x;
    const int bx = blockIdx.x % SPLITS;   // column split
    const int by = blockIdx.x / SPLITS;   // row block
    const int row0 = by * TM;
    const int col0 = bx * CPS;
    const int tx = tid & 15, ty = tid >> 4;
    const int lr = tid >> 2;              // tile row this thread stages
    const int lk = (tid & 3) << 2;        // k offset (float4)

    float m_run[4], s_run[4];
#pragma unroll
    for (int r = 0; r < 4; r++) { m_run[r] = -INFINITY; s_run[r] = 0.f; }

    const float* aptr = img + (size_t)(row0 + lr) * DD + lk;

    for (int ct = 0; ct < CTILES; ct++) {
        const int c0 = col0 + ct * TN;
        const float* bptr = txt + (size_t)(c0 + lr) * DD + lk;
        float acc[4][4] = {};
        for (int kt = 0; kt < DD; kt += TK) {
            const float4 av = *(const float4*)(aptr + kt);
            const float4 bv = *(const float4*)(bptr + kt);
            __syncthreads();   // previous iteration's LDS reads done
            As[lk + 0][lr] = av.x; As[lk + 1][lr] = av.y;
            As[lk + 2][lr] = av.z; As[lk + 3][lr] = av.w;
            Bs[lk + 0][lr] = bv.x; Bs[lk + 1][lr] = bv.y;
            Bs[lk + 2][lr] = bv.z; Bs[lk + 3][lr] = bv.w;
            __syncthreads();
#pragma unroll
            for (int k = 0; k < TK; k++) {
                float a[4], b[4];
#pragma unroll
                for (int r = 0; r < 4; r++) a[r] = As[k][ty * 4 + r];
#pragma unroll
                for (int c = 0; c < 4; c++) b[c] = Bs[k][tx * 4 + c];
#pragma unroll
                for (int r = 0; r < 4; r++)
#pragma unroll
                    for (int c = 0; c < 4; c++)
                        acc[r][c] = fmaf(a[r], b[c], acc[r][c]);
            }
        }
        // per-row tile max + expsum, reduced across the 16 tx threads
#pragma unroll
        for (int r = 0; r < 4; r++) {
            const float l0 = acc[r][0] * scale, l1 = acc[r][1] * scale;
            const float l2 = acc[r][2] * scale, l3 = acc[r][3] * scale;
            float tmax = fmaxf(fmaxf(l0, l1), fmaxf(l2, l3));
#pragma unroll
            for (int off = 8; off; off >>= 1)
                tmax = fmaxf(tmax, __shfl_xor(tmax, off));
            float es = __expf(l0 - tmax) + __expf(l1 - tmax) +
                       __expf(l2 - tmax) + __expf(l3 - tmax);
#pragma unroll
            for (int off = 8; off; off >>= 1) es += __shfl_xor(es, off);
            const float mnew = fmaxf(m_run[r], tmax);
            s_run[r] = s_run[r] * __expf(m_run[r] - mnew) + es * __expf(tmax - mnew);
            m_run[r] = mnew;
        }
    }
    if (tx == 0) {
#pragma unroll
        for (int r = 0; r < 4; r++) {
            const size_t row = row0 + ty * 4 + r;
            pm[row * SPLITS + bx] = m_run[r];
            ps[row * SPLITS + bx] = s_run[r];
        }
    }
}

// ---------------------------------------------------------------------------
// Kernel 3: combine split partials -> lse, per-row dot products, loss reduce.
// 64 blocks x 256 threads (4 waves); one wave per row, 32 rows per wave.
// ---------------------------------------------------------------------------
__global__ __launch_bounds__(256) void k_finalize(
    const float* __restrict__ img, const float* __restrict__ txt,
    const int* __restrict__ labels, const float* __restrict__ scale_p,
    const float* __restrict__ Tsum, const int* __restrict__ counts,
    const float* __restrict__ pm, const float* __restrict__ ps,
    float* __restrict__ out)
{
    const float scale = scale_p[0];
    const int tid = threadIdx.x;
    const int lane = tid & 63;
    const int wave = tid >> 6;
    const int rowBase = blockIdx.x * 128 + wave * 32;
    float local = 0.f;
    for (int it = 0; it < 32; it++) {
        const int i = rowBase + it;
        const int lab = labels[i];
        float ds = 0.f, dt = 0.f;
        const float* ip = img + (size_t)i * DD;
        const float* tp = txt + (size_t)i * DD;
        const float* sp = Tsum + lab * DD;
#pragma unroll
        for (int k = lane; k < DD; k += 64) {
            const float a = ip[k];
            ds = fmaf(a, tp[k], ds);
            dt = fmaf(a, sp[k], dt);
        }
#pragma unroll
        for (int off = 32; off; off >>= 1) {
            ds += __shfl_xor(ds, off);
            dt += __shfl_xor(dt, off);
        }
        if (lane == 0) {
            float m = -INFINITY;
            for (int s = 0; s < SPLITS; s++)
                m = fmaxf(m, pm[(size_t)i * SPLITS + s]);
            float ssum = 0.f;
            for (int s = 0; s < SPLITS; s++)
                ssum += ps[(size_t)i * SPLITS + s] *
                        __expf(pm[(size_t)i * SPLITS + s] - m);
            const float lse = m + __logf(ssum);
            const int cnt = counts[lab] - 1;
            if (cnt > 0) {
                const float row_sum = scale * (dt - ds) - (float)cnt * lse;
                local += row_sum / (float)cnt;
            }
        }
    }
    __shared__ float red[4];
    if (lane == 0) red[wave] = local;
    __syncthreads();
    if (tid == 0) {
        const float t = red[0] + red[1] + red[2] + red[3];
        atomicAdd(out, -t / (float)NN);
    }
}

// ---------------------------------------------------------------------------
extern "C" void kernel_launch(void* const* d_in, const int* in_sizes, int n_in,
                              void* d_out, int out_size, void* d_ws, size_t ws_size,
                              hipStream_t stream)
{
    const float* img     = (const float*)d_in[0];
    const float* txt     = (const float*)d_in[1];
    const float* scale_p = (const float*)d_in[2];
    const int*   labels  = (const int*)d_in[3];
    float* out = (float*)d_out;

    char* ws = (char*)d_ws;
    float* Tsum  = (float*)ws;                                   // 16384 B
    int*   counts = (int*)(ws + NSRC * DD * 4);                  // 32 B
    float* pm = (float*)(ws + NSRC * DD * 4 + 32);               // 8192*8*4 B
    float* ps = (float*)(ws + NSRC * DD * 4 + 32 + NN * SPLITS * 4);

    hipMemsetAsync(d_out, 0, sizeof(float), stream);
    hipMemsetAsync(d_ws, 0, NSRC * DD * 4 + NSRC * 4, stream);

    k_src_sums<<<NN / 128, 256, 0, stream>>>(txt, labels, Tsum, counts);
    k_lse<<<(NN / TM) * SPLITS, 256, 0, stream>>>(img, txt, scale_p, pm, ps);
    k_finalize<<<NN / 128, 256, 0, stream>>>(img, txt, labels, scale_p,
                                             Tsum, counts, pm, ps, out);
}

// Round 2
// 242.172 us; speedup vs baseline: 4.7276x; 4.7276x over previous
//
#include <hip/hip_runtime.h>
#include <cmath>

#define NN 8192
#define DD 512
#define NSRC 8
#define SPLITS 16
#define BM 128
#define BN 128
#define BK 64
#define CPS (NN / SPLITS)     // 512 cols per split
#define CTILES (CPS / BN)     // 4 column tiles per block

typedef __bf16 bf16x8 __attribute__((ext_vector_type(8)));
typedef float  f32x4  __attribute__((ext_vector_type(4)));

__device__ __forceinline__ unsigned short f2bf(float f) {
    unsigned u = __float_as_uint(f);
    u += 0x7fffu + ((u >> 16) & 1u);
    return (unsigned short)(u >> 16);
}

// ---------------------------------------------------------------------------
// Kernel 0: fp32 -> bf16 cast of both feature matrices (RNE).
// ---------------------------------------------------------------------------
__global__ __launch_bounds__(256) void k_cast(
    const float* __restrict__ img, const float* __restrict__ txt,
    unsigned short* __restrict__ imgB, unsigned short* __restrict__ txtB)
{
    const size_t gid = (size_t)blockIdx.x * 256 + threadIdx.x;
    const size_t half = (size_t)NN * DD / 8;   // chunks of 8 elements
    const float* src = (gid < half) ? img : txt;
    unsigned short* dst = (gid < half) ? imgB : txtB;
    const size_t off = ((gid < half) ? gid : gid - half) * 8;
    const float4 v0 = *(const float4*)(src + off);
    const float4 v1 = *(const float4*)(src + off + 4);
    union { unsigned short s[8]; uint4 v; } o;
    o.s[0] = f2bf(v0.x); o.s[1] = f2bf(v0.y); o.s[2] = f2bf(v0.z); o.s[3] = f2bf(v0.w);
    o.s[4] = f2bf(v1.x); o.s[5] = f2bf(v1.y); o.s[6] = f2bf(v1.z); o.s[7] = f2bf(v1.w);
    *(uint4*)(dst + off) = o.v;
}

// ---------------------------------------------------------------------------
// Kernel 1: per-source text sums T[s][d] and per-source counts (fp32 path).
// ---------------------------------------------------------------------------
__global__ __launch_bounds__(256) void k_src_sums(
    const float* __restrict__ txt, const int* __restrict__ labels,
    float* __restrict__ Tsum, int* __restrict__ counts)
{
    __shared__ float Tacc[NSRC * DD];
    __shared__ int cacc[NSRC];
    const int tid = threadIdx.x;
    const int d0 = 2 * tid;
#pragma unroll
    for (int s = 0; s < NSRC; s++) {
        Tacc[s * DD + d0] = 0.f;
        Tacc[s * DD + d0 + 1] = 0.f;
    }
    if (tid < NSRC) cacc[tid] = 0;
    __syncthreads();

    const int row0 = blockIdx.x * 128;
    if (tid < 128) atomicAdd(&cacc[labels[row0 + tid]], 1);

    for (int j = 0; j < 128; j++) {
        const int lab = labels[row0 + j];
        const float2 v = *(const float2*)(txt + (size_t)(row0 + j) * DD + d0);
        Tacc[lab * DD + d0]     += v.x;
        Tacc[lab * DD + d0 + 1] += v.y;
    }
    __syncthreads();
#pragma unroll
    for (int s = 0; s < NSRC; s++) {
        atomicAdd(&Tsum[s * DD + d0],     Tacc[s * DD + d0]);
        atomicAdd(&Tsum[s * DD + d0 + 1], Tacc[s * DD + d0 + 1]);
    }
    if (tid < NSRC) atomicAdd(&counts[tid], cacc[tid]);
}

// ---------------------------------------------------------------------------
// Kernel 2: MFMA flash-lse. Block = 128 rows x 128-col tiles, BK=64.
// 4 waves; wave w owns rows w*32..w*32+31 (2 i-tiles) x 128 cols (8 j-tiles)
// -> online (m,s) state per row lives in registers, no cross-wave merge.
// LDS staged via global_load_lds width=16 with XOR k-chunk swizzle:
//   LDS chunk (r, c) holds global k-chunk (c ^ (r&7))  [16B chunks]
// so fragment ds_read_b128 is at most 2-way bank aliased (free).
// ---------------------------------------------------------------------------
__global__ __launch_bounds__(256) void k_lse_mfma(
    const unsigned short* __restrict__ imgB, const unsigned short* __restrict__ txtB,
    const float* __restrict__ scale_p,
    float* __restrict__ pm, float* __restrict__ ps)
{
    __shared__ uint4 lds[2048];            // A: [0,1024), B: [1024,2048) chunks
    const float scale = scale_p[0];
    const int tid  = threadIdx.x;
    const int lane = tid & 63;
    const int w    = tid >> 6;             // wave id
    const int split = blockIdx.x & (SPLITS - 1);
    const int by    = blockIdx.x / SPLITS;
    const int row0  = by * BM;
    const int colBase = split * CPS;
    const int lq = lane >> 4;              // quad within wave
    const int ln = lane & 15;

    // staging geometry: thread stages physical chunk p = t*256 + tid
    int st_r[4], st_kc[4];
#pragma unroll
    for (int t = 0; t < 4; t++) {
        const int p = t * 256 + tid;
        st_r[t]  = p >> 3;
        st_kc[t] = (p & 7) ^ (st_r[t] & 7);
    }

    // fragment read bases (uint4 chunk indices)
    int aIdx[2], aSw[2], bIdx[8], bSw[8];
#pragma unroll
    for (int i = 0; i < 2; i++) {
        const int r = w * 32 + i * 16 + ln;
        aIdx[i] = r * 8; aSw[i] = r & 7;
    }
#pragma unroll
    for (int j = 0; j < 8; j++) {
        const int r = j * 16 + ln;
        bIdx[j] = 1024 + r * 8; bSw[j] = r & 7;
    }

    float m_run[2][4], s_run[2][4];
#pragma unroll
    for (int i = 0; i < 2; i++)
#pragma unroll
        for (int rg = 0; rg < 4; rg++) { m_run[i][rg] = -INFINITY; s_run[i][rg] = 0.f; }

    for (int ct = 0; ct < CTILES; ct++) {
        const int col0 = colBase + ct * BN;
        f32x4 acc[2][8];
#pragma unroll
        for (int i = 0; i < 2; i++)
#pragma unroll
            for (int j = 0; j < 8; j++) acc[i][j] = (f32x4){0.f, 0.f, 0.f, 0.f};

        for (int kt = 0; kt < DD; kt += BK) {
            __syncthreads();               // previous tile's LDS reads done
#pragma unroll
            for (int t = 0; t < 4; t++) {  // stage A (128x64 bf16)
                const unsigned short* g =
                    imgB + (size_t)(row0 + st_r[t]) * DD + kt + (st_kc[t] << 3);
                __builtin_amdgcn_global_load_lds(
                    (const __attribute__((address_space(1))) void*)g,
                    (__attribute__((address_space(3))) void*)&lds[t * 256 + (w << 6)],
                    16, 0, 0);
            }
#pragma unroll
            for (int t = 0; t < 4; t++) {  // stage B (128 cols x 64 bf16)
                const unsigned short* g =
                    txtB + (size_t)(col0 + st_r[t]) * DD + kt + (st_kc[t] << 3);
                __builtin_amdgcn_global_load_lds(
                    (const __attribute__((address_space(1))) void*)g,
                    (__attribute__((address_space(3))) void*)&lds[1024 + t * 256 + (w << 6)],
                    16, 0, 0);
            }
            __syncthreads();               // drain global_load_lds
#pragma unroll
            for (int ks = 0; ks < 2; ks++) {
                bf16x8 af[2], bf[8];
#pragma unroll
                for (int i = 0; i < 2; i++)
                    af[i] = *reinterpret_cast<const bf16x8*>(
                        &lds[aIdx[i] + (((ks << 2) + lq) ^ aSw[i])]);
#pragma unroll
                for (int j = 0; j < 8; j++)
                    bf[j] = *reinterpret_cast<const bf16x8*>(
                        &lds[bIdx[j] + (((ks << 2) + lq) ^ bSw[j])]);
#pragma unroll
                for (int i = 0; i < 2; i++)
#pragma unroll
                    for (int j = 0; j < 8; j++)
                        acc[i][j] = __builtin_amdgcn_mfma_f32_16x16x32_bf16(
                            af[i], bf[j], acc[i][j], 0, 0, 0);
            }
        }
        // epilogue: per-row (over this 128-col tile) max + expsum, shuffle-only.
        // C layout: col = ln, row-in-tile = lq*4 + rg  (m89-verified)
#pragma unroll
        for (int i = 0; i < 2; i++)
#pragma unroll
        for (int rg = 0; rg < 4; rg++) {
            float v[8];
#pragma unroll
            for (int j = 0; j < 8; j++) v[j] = acc[i][j][rg] * scale;
            float tmax = v[0];
#pragma unroll
            for (int j = 1; j < 8; j++) tmax = fmaxf(tmax, v[j]);
#pragma unroll
            for (int off = 8; off; off >>= 1) tmax = fmaxf(tmax, __shfl_xor(tmax, off));
            float es = 0.f;
#pragma unroll
            for (int j = 0; j < 8; j++) es += __expf(v[j] - tmax);
#pragma unroll
            for (int off = 8; off; off >>= 1) es += __shfl_xor(es, off);
            const float mold = m_run[i][rg];
            const float mnew = fmaxf(mold, tmax);
            s_run[i][rg] = s_run[i][rg] * __expf(mold - mnew) + es * __expf(tmax - mnew);
            m_run[i][rg] = mnew;
        }
    }
    if (ln == 0) {
#pragma unroll
        for (int i = 0; i < 2; i++)
#pragma unroll
        for (int rg = 0; rg < 4; rg++) {
            const int row = row0 + w * 32 + i * 16 + lq * 4 + rg;
            pm[(size_t)row * SPLITS + split] = m_run[i][rg];
            ps[(size_t)row * SPLITS + split] = s_run[i][rg];
        }
    }
}

// ---------------------------------------------------------------------------
// Kernel 3: combine split partials -> lse, per-row fp32 dot products, reduce.
// ---------------------------------------------------------------------------
__global__ __launch_bounds__(256) void k_finalize(
    const float* __restrict__ img, const float* __restrict__ txt,
    const int* __restrict__ labels, const float* __restrict__ scale_p,
    const float* __restrict__ Tsum, const int* __restrict__ counts,
    const float* __restrict__ pm, const float* __restrict__ ps,
    float* __restrict__ out)
{
    const float scale = scale_p[0];
    const int tid = threadIdx.x;
    const int lane = tid & 63;
    const int wave = tid >> 6;
    const int rowBase = blockIdx.x * 128 + wave * 32;
    float local = 0.f;
    for (int it = 0; it < 32; it++) {
        const int i = rowBase + it;
        const int lab = labels[i];
        float ds = 0.f, dt = 0.f;
        const float* ip = img + (size_t)i * DD;
        const float* tp = txt + (size_t)i * DD;
        const float* sp = Tsum + lab * DD;
#pragma unroll
        for (int k = lane; k < DD; k += 64) {
            const float a = ip[k];
            ds = fmaf(a, tp[k], ds);
            dt = fmaf(a, sp[k], dt);
        }
#pragma unroll
        for (int off = 32; off; off >>= 1) {
            ds += __shfl_xor(ds, off);
            dt += __shfl_xor(dt, off);
        }
        if (lane == 0) {
            float m = -INFINITY;
            for (int s = 0; s < SPLITS; s++)
                m = fmaxf(m, pm[(size_t)i * SPLITS + s]);
            float ssum = 0.f;
            for (int s = 0; s < SPLITS; s++)
                ssum += ps[(size_t)i * SPLITS + s] *
                        __expf(pm[(size_t)i * SPLITS + s] - m);
            const float lse = m + __logf(ssum);
            const int cnt = counts[lab] - 1;
            if (cnt > 0) {
                const float row_sum = scale * (dt - ds) - (float)cnt * lse;
                local += row_sum / (float)cnt;
            }
        }
    }
    __shared__ float red[4];
    if (lane == 0) red[wave] = local;
    __syncthreads();
    if (tid == 0) {
        const float t = red[0] + red[1] + red[2] + red[3];
        atomicAdd(out, -t / (float)NN);
    }
}

// ---------------------------------------------------------------------------
extern "C" void kernel_launch(void* const* d_in, const int* in_sizes, int n_in,
                              void* d_out, int out_size, void* d_ws, size_t ws_size,
                              hipStream_t stream)
{
    const float* img     = (const float*)d_in[0];
    const float* txt     = (const float*)d_in[1];
    const float* scale_p = (const float*)d_in[2];
    const int*   labels  = (const int*)d_in[3];
    float* out = (float*)d_out;

    char* ws = (char*)d_ws;
    float* pm    = (float*)(ws);                                  // 512 KB
    float* ps    = (float*)(ws + (size_t)NN * SPLITS * 4);        // 512 KB
    float* Tsum  = (float*)(ws + (size_t)2 * NN * SPLITS * 4);    // 16 KB
    int*   counts = (int*)(ws + (size_t)2 * NN * SPLITS * 4 + NSRC * DD * 4);
    unsigned short* imgB = (unsigned short*)(ws + 2 * 1024 * 1024);       // 8 MB
    unsigned short* txtB = (unsigned short*)(ws + 10 * 1024 * 1024);      // 8 MB

    hipMemsetAsync(d_out, 0, sizeof(float), stream);
    hipMemsetAsync(Tsum, 0, NSRC * DD * 4 + NSRC * 4, stream);

    k_cast<<<(2 * NN * DD / 8) / 256, 256, 0, stream>>>(img, txt, imgB, txtB);
    k_src_sums<<<NN / 128, 256, 0, stream>>>(txt, labels, Tsum, counts);
    k_lse_mfma<<<(NN / BM) * SPLITS, 256, 0, stream>>>(imgB, txtB, scale_p, pm, ps);
    k_finalize<<<NN / 128, 256, 0, stream>>>(img, txt, labels, scale_p,
                                             Tsum, counts, pm, ps, out);
}

// Round 3
// 188.026 us; speedup vs baseline: 6.0891x; 1.2880x over previous
//
#include <hip/hip_runtime.h>
#include <cmath>

#define NN 8192
#define DD 512
#define NSRC 8
#define SPLITS 16
#define BM 128
#define BN 128
#define BK 64
#define CPS (NN / SPLITS)     // 512 cols per split
#define CTILES (CPS / BN)     // 4 column tiles per block
#define COFF 100.0f           // fixed softmax offset (see theory: no online max)

typedef __bf16 bf16x8 __attribute__((ext_vector_type(8)));
typedef float  f32x4  __attribute__((ext_vector_type(4)));

__device__ __forceinline__ unsigned short f2bf(float f) {
    unsigned u = __float_as_uint(f);
    u += 0x7fffu + ((u >> 16) & 1u);
    return (unsigned short)(u >> 16);
}

// ---------------------------------------------------------------------------
// Kernel 0: fp32 -> bf16 cast of both feature matrices (RNE).
// Block 0 additionally zero-inits Tsum / counts / out (stream order guarantees
// completion before k_src_sums' atomics and k_finalize's atomics).
// ---------------------------------------------------------------------------
__global__ __launch_bounds__(256) void k_cast(
    const float* __restrict__ img, const float* __restrict__ txt,
    unsigned short* __restrict__ imgB, unsigned short* __restrict__ txtB,
    float* __restrict__ Tsum, int* __restrict__ counts, float* __restrict__ out)
{
    if (blockIdx.x == 0) {
        // zero Tsum (4096 floats), counts (8 ints), out (1 float)
        float4 z = {0.f, 0.f, 0.f, 0.f};
#pragma unroll
        for (int k = 0; k < 4; k++)
            *(float4*)(Tsum + (k * 256 + threadIdx.x) * 4) = z;
        if (threadIdx.x < NSRC) counts[threadIdx.x] = 0;
        if (threadIdx.x == 0) out[0] = 0.f;
    }
    const size_t gid = (size_t)blockIdx.x * 256 + threadIdx.x;
    const size_t half = (size_t)NN * DD / 8;   // chunks of 8 elements
    const float* src = (gid < half) ? img : txt;
    unsigned short* dst = (gid < half) ? imgB : txtB;
    const size_t off = ((gid < half) ? gid : gid - half) * 8;
    const float4 v0 = *(const float4*)(src + off);
    const float4 v1 = *(const float4*)(src + off + 4);
    union { unsigned short s[8]; uint4 v; } o;
    o.s[0] = f2bf(v0.x); o.s[1] = f2bf(v0.y); o.s[2] = f2bf(v0.z); o.s[3] = f2bf(v0.w);
    o.s[4] = f2bf(v1.x); o.s[5] = f2bf(v1.y); o.s[6] = f2bf(v1.z); o.s[7] = f2bf(v1.w);
    *(uint4*)(dst + off) = o.v;
}

// ---------------------------------------------------------------------------
// Kernel 1: per-source text sums T[s][d] and per-source counts.
// 128 blocks x 256 threads; each block owns 64 rows; thread owns 2 d-cols.
// ---------------------------------------------------------------------------
__global__ __launch_bounds__(256) void k_src_sums(
    const float* __restrict__ txt, const int* __restrict__ labels,
    float* __restrict__ Tsum, int* __restrict__ counts)
{
    __shared__ float Tacc[NSRC * DD];
    __shared__ int cacc[NSRC];
    const int tid = threadIdx.x;
    const int d0 = 2 * tid;
#pragma unroll
    for (int s = 0; s < NSRC; s++) {
        Tacc[s * DD + d0] = 0.f;
        Tacc[s * DD + d0 + 1] = 0.f;
    }
    if (tid < NSRC) cacc[tid] = 0;
    __syncthreads();

    const int row0 = blockIdx.x * 64;
    if (tid < 64) atomicAdd(&cacc[labels[row0 + tid]], 1);

    for (int j = 0; j < 64; j++) {
        const int lab = labels[row0 + j];
        const float2 v = *(const float2*)(txt + (size_t)(row0 + j) * DD + d0);
        Tacc[lab * DD + d0]     += v.x;
        Tacc[lab * DD + d0 + 1] += v.y;
    }
    __syncthreads();
    // coalesced flush: entry e = k*256 + tid
#pragma unroll
    for (int k = 0; k < NSRC * DD / 256; k++) {
        const int e = k * 256 + tid;
        atomicAdd(&Tsum[e], Tacc[e]);
    }
    if (tid < NSRC) atomicAdd(&counts[tid], cacc[tid]);
}

// ---------------------------------------------------------------------------
// Kernel 2: MFMA flash-lse with FIXED offset (no online max).
// Block = 128 rows x 512-col split, BK=64; 4 waves, wave owns 32 rows x 128
// cols (2 i-tiles x 8 j-tiles of 16x16x32 MFMA). Per-lane expsum partials
// accumulate across col tiles in registers; one 4-shuffle reduce at the end.
// LDS staged via global_load_lds width=16 with XOR k-chunk swizzle (R2:
// verified 0 bank conflicts).
// ---------------------------------------------------------------------------
__global__ __launch_bounds__(256) void k_lse_mfma(
    const unsigned short* __restrict__ imgB, const unsigned short* __restrict__ txtB,
    const float* __restrict__ scale_p,
    float* __restrict__ ps)
{
    __shared__ uint4 lds[2048];            // A: [0,1024), B: [1024,2048) chunks
    const float scale = scale_p[0];
    const int tid  = threadIdx.x;
    const int lane = tid & 63;
    const int w    = tid >> 6;             // wave id
    const int split = blockIdx.x & (SPLITS - 1);
    const int by    = blockIdx.x / SPLITS;
    const int row0  = by * BM;
    const int colBase = split * CPS;
    const int lq = lane >> 4;              // quad within wave
    const int ln = lane & 15;

    // staging geometry: thread stages physical chunk p = t*256 + tid
    int st_r[4], st_kc[4];
#pragma unroll
    for (int t = 0; t < 4; t++) {
        const int p = t * 256 + tid;
        st_r[t]  = p >> 3;
        st_kc[t] = (p & 7) ^ (st_r[t] & 7);
    }

    // fragment read bases (uint4 chunk indices)
    int aIdx[2], aSw[2], bIdx[8], bSw[8];
#pragma unroll
    for (int i = 0; i < 2; i++) {
        const int r = w * 32 + i * 16 + ln;
        aIdx[i] = r * 8; aSw[i] = r & 7;
    }
#pragma unroll
    for (int j = 0; j < 8; j++) {
        const int r = j * 16 + ln;
        bIdx[j] = 1024 + r * 8; bSw[j] = r & 7;
    }

    float s_run[2][4];
#pragma unroll
    for (int i = 0; i < 2; i++)
#pragma unroll
        for (int rg = 0; rg < 4; rg++) s_run[i][rg] = 0.f;

    for (int ct = 0; ct < CTILES; ct++) {
        const int col0 = colBase + ct * BN;
        f32x4 acc[2][8];
#pragma unroll
        for (int i = 0; i < 2; i++)
#pragma unroll
            for (int j = 0; j < 8; j++) acc[i][j] = (f32x4){0.f, 0.f, 0.f, 0.f};

        for (int kt = 0; kt < DD; kt += BK) {
            __syncthreads();               // previous tile's LDS reads done
#pragma unroll
            for (int t = 0; t < 4; t++) {  // stage A (128x64 bf16)
                const unsigned short* g =
                    imgB + (size_t)(row0 + st_r[t]) * DD + kt + (st_kc[t] << 3);
                __builtin_amdgcn_global_load_lds(
                    (const __attribute__((address_space(1))) void*)g,
                    (__attribute__((address_space(3))) void*)&lds[t * 256 + (w << 6)],
                    16, 0, 0);
            }
#pragma unroll
            for (int t = 0; t < 4; t++) {  // stage B (128 cols x 64 bf16)
                const unsigned short* g =
                    txtB + (size_t)(col0 + st_r[t]) * DD + kt + (st_kc[t] << 3);
                __builtin_amdgcn_global_load_lds(
                    (const __attribute__((address_space(1))) void*)g,
                    (__attribute__((address_space(3))) void*)&lds[1024 + t * 256 + (w << 6)],
                    16, 0, 0);
            }
            __syncthreads();               // drain global_load_lds
#pragma unroll
            for (int ks = 0; ks < 2; ks++) {
                bf16x8 af[2], bf[8];
#pragma unroll
                for (int i = 0; i < 2; i++)
                    af[i] = *reinterpret_cast<const bf16x8*>(
                        &lds[aIdx[i] + (((ks << 2) + lq) ^ aSw[i])]);
#pragma unroll
                for (int j = 0; j < 8; j++)
                    bf[j] = *reinterpret_cast<const bf16x8*>(
                        &lds[bIdx[j] + (((ks << 2) + lq) ^ bSw[j])]);
#pragma unroll
                for (int i = 0; i < 2; i++)
#pragma unroll
                    for (int j = 0; j < 8; j++)
                        acc[i][j] = __builtin_amdgcn_mfma_f32_16x16x32_bf16(
                            af[i], bf[j], acc[i][j], 0, 0, 0);
            }
        }
        // epilogue: exp(logit - COFF), per-lane accumulation only (no shuffles)
#pragma unroll
        for (int i = 0; i < 2; i++)
#pragma unroll
        for (int rg = 0; rg < 4; rg++) {
            float es = s_run[i][rg];
#pragma unroll
            for (int j = 0; j < 8; j++)
                es += __expf(fmaf(acc[i][j][rg], scale, -COFF));
            s_run[i][rg] = es;
        }
    }
    // cross-lane reduce over the 16 ln positions (stays within lq group)
#pragma unroll
    for (int i = 0; i < 2; i++)
#pragma unroll
    for (int rg = 0; rg < 4; rg++) {
        float es = s_run[i][rg];
#pragma unroll
        for (int off = 8; off; off >>= 1) es += __shfl_xor(es, off);
        s_run[i][rg] = es;
    }
    if (ln == 0) {
#pragma unroll
        for (int i = 0; i < 2; i++)
#pragma unroll
        for (int rg = 0; rg < 4; rg++) {
            const int row = row0 + w * 32 + i * 16 + lq * 4 + rg;
            ps[(size_t)row * SPLITS + split] = s_run[i][rg];
        }
    }
}

// ---------------------------------------------------------------------------
// Kernel 3: combine split partials -> lse, per-row fp32 dot products, reduce.
// 512 blocks x 4 waves x 4 rows.
// ---------------------------------------------------------------------------
__global__ __launch_bounds__(256) void k_finalize(
    const float* __restrict__ img, const float* __restrict__ txt,
    const int* __restrict__ labels, const float* __restrict__ scale_p,
    const float* __restrict__ Tsum, const int* __restrict__ counts,
    const float* __restrict__ ps,
    float* __restrict__ out)
{
    const float scale = scale_p[0];
    const int tid = threadIdx.x;
    const int lane = tid & 63;
    const int wave = tid >> 6;
    const int rowBase = blockIdx.x * 16 + wave * 4;
    float local = 0.f;
#pragma unroll
    for (int it = 0; it < 4; it++) {
        const int i = rowBase + it;
        const int lab = labels[i];
        float ds = 0.f, dt = 0.f;
        const float* ip = img + (size_t)i * DD;
        const float* tp = txt + (size_t)i * DD;
        const float* sp = Tsum + lab * DD;
#pragma unroll
        for (int k = lane; k < DD; k += 64) {
            const float a = ip[k];
            ds = fmaf(a, tp[k], ds);
            dt = fmaf(a, sp[k], dt);
        }
#pragma unroll
        for (int off = 32; off; off >>= 1) {
            ds += __shfl_xor(ds, off);
            dt += __shfl_xor(dt, off);
        }
        if (lane == 0) {
            float ssum = 0.f;
#pragma unroll
            for (int s = 0; s < SPLITS; s++)
                ssum += ps[(size_t)i * SPLITS + s];
            const float lse = COFF + __logf(ssum);
            const int cnt = counts[lab] - 1;
            if (cnt > 0) {
                const float row_sum = scale * (dt - ds) - (float)cnt * lse;
                local += row_sum / (float)cnt;
            }
        }
    }
    __shared__ float red[4];
    if (lane == 0) red[wave] = local;
    __syncthreads();
    if (tid == 0) {
        const float t = red[0] + red[1] + red[2] + red[3];
        atomicAdd(out, -t / (float)NN);
    }
}

// ---------------------------------------------------------------------------
extern "C" void kernel_launch(void* const* d_in, const int* in_sizes, int n_in,
                              void* d_out, int out_size, void* d_ws, size_t ws_size,
                              hipStream_t stream)
{
    const float* img     = (const float*)d_in[0];
    const float* txt     = (const float*)d_in[1];
    const float* scale_p = (const float*)d_in[2];
    const int*   labels  = (const int*)d_in[3];
    float* out = (float*)d_out;

    char* ws = (char*)d_ws;
    float* ps    = (float*)(ws);                                  // 512 KB
    float* Tsum  = (float*)(ws + (size_t)NN * SPLITS * 4);        // 16 KB
    int*   counts = (int*)(ws + (size_t)NN * SPLITS * 4 + NSRC * DD * 4);
    unsigned short* imgB = (unsigned short*)(ws + 2 * 1024 * 1024);       // 8 MB
    unsigned short* txtB = (unsigned short*)(ws + 10 * 1024 * 1024);      // 8 MB

    k_cast<<<(2 * NN * DD / 8) / 256, 256, 0, stream>>>(img, txt, imgB, txtB,
                                                        Tsum, counts, out);
    k_src_sums<<<NN / 64, 256, 0, stream>>>(txt, labels, Tsum, counts);
    k_lse_mfma<<<(NN / BM) * SPLITS, 256, 0, stream>>>(imgB, txtB, scale_p, ps);
    k_finalize<<<NN / 16, 256, 0, stream>>>(img, txt, labels, scale_p,
                                            Tsum, counts, ps, out);
}